// Round 1
// baseline (111.503 us; speedup 1.0000x reference)
//
#include <hip/hip_runtime.h>
#include <math.h>

// Problem constants
#define NB    256           // N nodes
#define EDIM  16            // edge MLP hidden
#define FINN  32            // Fin
#define FOUTN 32            // Fout
#define BT    128           // B*T

// The whole op is one GEMM:  C[i,(bt,o)] = H[i,(e,j)] @ y2[(e,j),(bt,o)]
//   H[i, e*256+j]  = gelu(adj[i,j]*w1[e]+b1[e])                (2 MiB bf16)
//   y2[(e,j),(bt,o)] = sum_f x[bt,j,f] * w2[e,f,o]             (32 MiB bf16)
// plus out = gelu(C + x@node_w + node_b + (sum_j x)@b2).
// prep_kernel materializes H (A-fragment order) and y2 (B-fragment order)
// ONCE; fused_kernel is then a pure streaming GEMM (A-frags register-direct
// from L2, B-frags via global_load_lds -> LDS, conflict-free lane*16B reads).

typedef __attribute__((ext_vector_type(8))) short short8;   // 8 bf16 = 4 VGPRs
typedef __attribute__((ext_vector_type(4))) float floatx4;  // MFMA accumulator

#define MFMA16(a,b,c) __builtin_amdgcn_mfma_f32_16x16x32_bf16((a),(b),(c),0,0,0)

__device__ __forceinline__ float gelu_f(float v) {
    return 0.5f * v * (1.0f + erff(v * 0.70710678118654752f));
}
__device__ __forceinline__ ushort f2bf(float x) {
    union { float f; unsigned u; } v; v.f = x;
    unsigned r = (v.u + 0x7FFFu + ((v.u >> 16) & 1u)) >> 16;
    return (ushort)r;
}
__device__ __forceinline__ uint2 pack4(floatx4 d) {
    uint2 p;
    p.x = (unsigned)f2bf(d[0]) | ((unsigned)f2bf(d[1]) << 16);
    p.y = (unsigned)f2bf(d[2]) | ((unsigned)f2bf(d[3]) << 16);
    return p;
}

typedef __attribute__((address_space(1))) void gvoid_t;
typedef __attribute__((address_space(3))) void lvoid_t;
__device__ __forceinline__ void gload_lds16(const void* g, void* l) {
    // async global->LDS, 16B/lane; LDS dest is wave-uniform base + lane*16.
    __builtin_amdgcn_global_load_lds((gvoid_t*)g, (lvoid_t*)l, 16, 0, 0);
}

// ---------------------------------------------------------------------------
// prep_kernel, grid 1153 x 256 thr:
//   blocks [0,1024):   y2f  (bt = bid>>3, e-pair = bid&7); ep==0 also bias2g
//   blocks [1024,1152): Hf  (A-fragment order; identical to verified h_kernel)
//   block  1152:        nwf (node_w in B-fragment order, 2 frags)
// ---------------------------------------------------------------------------
__global__ __launch_bounds__(256) void prep_kernel(
        const float* __restrict__ x,   const float* __restrict__ adj,
        const float* __restrict__ w1,  const float* __restrict__ b1,
        const float* __restrict__ w2,  const float* __restrict__ b2,
        const float* __restrict__ node_w, const float* __restrict__ node_b,
        ushort* __restrict__ Hf, ushort* __restrict__ y2f,
        float* __restrict__ bias2g, ushort* __restrict__ nwf) {
    int bid = blockIdx.x;
    int tid = threadIdx.x;
    __shared__ float adjs[16][264];
    __shared__ float w1s[16], b1s[16];
    __shared__ float Sp[8][32];
    __shared__ float Svs[32];

    if (bid < 1024) {
        // ---- y2: block (bt, ep) covers e in {2ep, 2ep+1}, all 256 j ----
        int bt = bid >> 3, ep = bid & 7;
        int wv = tid >> 6, lane = tid & 63, m = lane & 15, quad = lane >> 4;
        // x A-fragments for this wave's 4 j-tiles (K = f = 32)
        short8 xf[4];
        #pragma unroll
        for (int t = 0; t < 4; ++t) {
            int jt = wv * 4 + t;
            const float* xs = x + ((size_t)bt * NB + jt * 16 + m) * FINN + quad * 8;
            float4 lo = *(const float4*)xs;
            float4 hi = *(const float4*)(xs + 4);
            ushort tmp[8];
            tmp[0]=f2bf(lo.x); tmp[1]=f2bf(lo.y); tmp[2]=f2bf(lo.z); tmp[3]=f2bf(lo.w);
            tmp[4]=f2bf(hi.x); tmp[5]=f2bf(hi.y); tmp[6]=f2bf(hi.z); tmp[7]=f2bf(hi.w);
            xf[t] = *(short8*)tmp;
        }
        #pragma unroll
        for (int ee = 0; ee < 2; ++ee) {
            int e = ep * 2 + ee;
            // w2 B-fragments (B[f][o]) for both o-halves, from f32 directly
            short8 wf[2];
            #pragma unroll
            for (int ot = 0; ot < 2; ++ot) {
                ushort tmp[8];
                #pragma unroll
                for (int d = 0; d < 8; ++d)
                    tmp[d] = f2bf(w2[(size_t)e * 1024 + (quad * 8 + d) * 32 + ot * 16 + m]);
                wf[ot] = *(short8*)tmp;
            }
            #pragma unroll
            for (int t = 0; t < 4; ++t) {
                int jt = wv * 4 + t;
                floatx4 z = {0.f, 0.f, 0.f, 0.f};
                floatx4 d0 = MFMA16(xf[t], wf[0], z);   // D[j-in-tile][o<16]
                floatx4 d1 = MFMA16(xf[t], wf[1], z);   // D[j-in-tile][o>=16]
                // scatter into main-GEMM B-fragment order:
                //   y2f[bt][ks][ot][lane'=(qp,m)][dp..dp+3], ks = e*8 + jt/2
                int ks = e * 8 + (jt >> 1);
                int qp = (jt & 1) * 2 + (quad >> 1);
                int dp = (quad & 1) * 4;
                size_t base = ((size_t)bt * 128 + ks) * 1024;
                *(uint2*)(y2f + base +       (qp * 16 + m) * 8 + dp) = pack4(d0);
                *(uint2*)(y2f + base + 512 + (qp * 16 + m) * 8 + dp) = pack4(d1);
            }
        }
        if (ep == 0) {
            // bias2[bt][o] = node_b[o] + sum_f (sum_j x[bt,j,f]) * b2[f,o]
            int f = tid & 31, grp = tid >> 5;
            float s = 0.f;
            for (int j = grp; j < NB; j += 8)
                s += x[((size_t)bt * NB + j) * FINN + f];
            Sp[grp][f] = s;
            __syncthreads();
            if (tid < 32) {
                float s2 = 0.f;
                #pragma unroll
                for (int g = 0; g < 8; ++g) s2 += Sp[g][tid];
                Svs[tid] = s2;
            }
            __syncthreads();
            if (tid < 32) {
                float bb = node_b[tid];
                #pragma unroll
                for (int f2 = 0; f2 < FINN; ++f2)
                    bb += Svs[f2] * b2[f2 * FOUTN + tid];
                bias2g[bt * 32 + tid] = bb;
            }
        }
        return;
    }
    if (bid < 1152) {
        // ---- H in MFMA A-fragment order (verified h_kernel body) ----
        int hb = bid - 1024;
        int it = hb & 15;
        int kq = hb >> 4;               // 0..7
        if (tid < 16) { w1s[tid] = w1[tid]; b1s[tid] = b1[tid]; }
        #pragma unroll
        for (int q = 0; q < 4; ++q) {
            int u = q * 256 + tid;
            int row = u >> 6, c4 = u & 63;
            *(float4*)&adjs[row][c4 * 4] =
                ((const float4*)(adj + ((size_t)it * 16 + row) * 256))[c4];
        }
        __syncthreads();
        #pragma unroll
        for (int q = 0; q < 4; ++q) {
            int u = q * 256 + tid;          // 16 ks x 64 lanes
            int ks = kq * 16 + (u >> 6);
            int lane = u & 63;
            int m = lane & 15, quad = lane >> 4;
            int e = ks >> 3;
            int j0 = (ks & 7) * 32 + quad * 8;
            float w = w1s[e], b = b1s[e];
            ushort tmp[8];
            #pragma unroll
            for (int d = 0; d < 8; ++d)
                tmp[d] = f2bf(gelu_f(adjs[m][j0 + d] * w + b));
            *(int4*)(Hf + (((size_t)it * 128 + ks) * 64 + lane) * 8) = *(int4*)tmp;
        }
        return;
    }
    // ---- node_w B-fragments (B[f][o]), 2 frags = 128 lanes ----
    if (tid < 128) {
        int ot = tid >> 6, lane = tid & 63, m = lane & 15, q = lane >> 4;
        ushort tmp[8];
        #pragma unroll
        for (int d = 0; d < 8; ++d)
            tmp[d] = f2bf(node_w[(q * 8 + d) * 32 + ot * 16 + m]);
        *(int4*)(nwf + tid * 8) = *(int4*)tmp;
    }
}

// ---------------------------------------------------------------------------
// fused_kernel: pure streaming GEMM + epilogue.
// grid (128 bt, 2 iq2) x 512 thr = 8 waves (wave -> i-tile it = iq2*8+wv).
// K = 128 k-slices, 8 chunks of 16. Per chunk: stage next y2 chunk (32 KB)
// via global_load_lds into the other LDS buffer, then 16x{a-frag from L2,
// 2 b-frag ds_read_b128 (linear, conflict-free), 2 MFMA}, one barrier.
// ---------------------------------------------------------------------------
__global__ __launch_bounds__(512, 2) void fused_kernel(
        const float* __restrict__ x,      const ushort* __restrict__ Hf,
        const ushort* __restrict__ y2f,   const float* __restrict__ bias2g,
        const ushort* __restrict__ nwf,   float* __restrict__ out) {
    __shared__ ushort Bsl[2][16][2][64][8];   // 64 KiB double-buffered y2 chunk

    int bt   = blockIdx.x;              // 0..127
    int iq2  = blockIdx.y;              // 0..1
    int tid  = threadIdx.x;
    int wv   = tid >> 6;                // 0..7
    int lane = tid & 63;
    int m    = lane & 15;
    int quad = lane >> 4;
    int it   = iq2 * 8 + wv;            // wave's i-tile (16 rows)
    int i0g  = it * 16;

    const ushort* Hlane = Hf + (size_t)it * 65536 + lane * 8;   // A-frag stream
    const ushort* y2bt  = y2f + (size_t)bt * 131072;            // this bt's B

    floatx4 acc[2] = {};

    #define STAGE(buf, c)                                                     \
    {                                                                         \
        const ushort* s_ = y2bt + (size_t)(c) * 16384;                        \
        ushort* d_ = &Bsl[buf][0][0][0][0];                                   \
        _Pragma("unroll")                                                     \
        for (int s = 0; s < 4; ++s)                                           \
            gload_lds16(s_ + s * 4096 + tid * 8, d_ + s * 4096 + tid * 8);    \
    }
    #define GEMMC(buf, c)                                                     \
    {                                                                         \
        _Pragma("unroll")                                                     \
        for (int kk = 0; kk < 16; ++kk) {                                     \
            short8 a  = *(const short8*)(Hlane + ((c) * 16 + kk) * 512);      \
            short8 b0 = *(const short8*)&Bsl[buf][kk][0][lane][0];            \
            short8 b1 = *(const short8*)&Bsl[buf][kk][1][lane][0];            \
            acc[0] = MFMA16(a, b0, acc[0]);                                   \
            acc[1] = MFMA16(a, b1, acc[1]);                                   \
        }                                                                     \
    }

    STAGE(0, 0);
    __syncthreads();                    // drain stage-0 (vmcnt) + barrier
    #pragma unroll
    for (int c = 0; c < 8; ++c) {
        if (c < 7) STAGE((c + 1) & 1, c + 1);   // overlaps compute below
        GEMMC(c & 1, c);
        __syncthreads();                // buf-reuse guard + stage(c+1) drain
    }

    // ---- epilogue: + x@node_w (via MFMA) + bias2, gelu, store ----
    short8 xa;
    {
        const float* xs = x + ((size_t)bt * NB + i0g + m) * FINN + quad * 8;
        float4 lo = *(const float4*)xs;
        float4 hi = *(const float4*)(xs + 4);
        ushort tmp[8];
        tmp[0]=f2bf(lo.x); tmp[1]=f2bf(lo.y); tmp[2]=f2bf(lo.z); tmp[3]=f2bf(lo.w);
        tmp[4]=f2bf(hi.x); tmp[5]=f2bf(hi.y); tmp[6]=f2bf(hi.z); tmp[7]=f2bf(hi.w);
        xa = *(short8*)tmp;
    }
    #pragma unroll
    for (int tn = 0; tn < 2; ++tn) {
        short8 nb = *(const short8*)(nwf + (tn * 64 + lane) * 8);
        acc[tn] = MFMA16(xa, nb, acc[tn]);
    }
    #pragma unroll
    for (int tn = 0; tn < 2; ++tn) {
        int o = tn * 16 + m;
        float bz = bias2g[bt * 32 + o];
        #pragma unroll
        for (int r = 0; r < 4; ++r) {
            int row = i0g + quad * 4 + r;
            out[((size_t)bt * NB + row) * FOUTN + o] = gelu_f(acc[tn][r] + bz);
        }
    }
    #undef STAGE
    #undef GEMMC
}

// ---------------------------------------------------------------------------
extern "C" void kernel_launch(void* const* d_in, const int* in_sizes, int n_in,
                              void* d_out, int out_size, void* d_ws, size_t ws_size,
                              hipStream_t stream) {
    const float* x      = (const float*)d_in[0];
    const float* adj    = (const float*)d_in[1];
    const float* w1     = (const float*)d_in[2];
    const float* b1     = (const float*)d_in[3];
    const float* w2     = (const float*)d_in[4];
    const float* b2     = (const float*)d_in[5];
    const float* node_w = (const float*)d_in[6];
    const float* node_b = (const float*)d_in[7];
    float* out = (float*)d_out;

    // Workspace layout (~34.1 MiB):
    ushort* Hf     = (ushort*)d_ws;                  // 2 MiB  (16*128*512)
    ushort* y2f    = Hf + (size_t)(1 << 20);         // 32 MiB (128*128*1024)
    float*  bias2g = (float*)(y2f + (size_t)(1 << 24)); // 16 KiB
    ushort* nwf    = (ushort*)(bias2g + 128 * 32);   // 2 KiB

    hipLaunchKernelGGL(prep_kernel, dim3(1153), dim3(256), 0, stream,
                       x, adj, w1, b1, w2, b2, node_w, node_b,
                       Hf, y2f, bias2g, nwf);
    hipLaunchKernelGGL(fused_kernel, dim3(BT, 2), dim3(512), 0, stream,
                       x, Hf, y2f, bias2g, nwf, out);
}